// Round 1
// baseline (549.075 us; speedup 1.0000x reference)
//
#include <hip/hip_runtime.h>

// ---------------------------------------------------------------------------
// Fused windowed attention (CrossFormer-style short-distance attention).
// B=2, D=256, H=W=256, window 8x8 -> 2048 windows, HEADS=8, DHEAD=32.
// One 512-thread block per window. bf16 MFMA (16x16x32), fp32 accumulate.
// ---------------------------------------------------------------------------

typedef __attribute__((ext_vector_type(8))) short bf16x8;
typedef __attribute__((ext_vector_type(4))) short bf16x4;
typedef __attribute__((ext_vector_type(4))) float f32x4;

__device__ __forceinline__ short f2b(float f) {
  union { float f; unsigned u; } v; v.f = f;
  unsigned r = v.u + 0x7FFFu + ((v.u >> 16) & 1u);  // RNE
  return (short)(r >> 16);
}

__device__ __forceinline__ void lnrelu_lds(float* h, const float* g, const float* be) {
  float m = 0.f;
  for (int f = 0; f < 64; ++f) m += h[f];
  m *= (1.f / 64.f);
  float v = 0.f;
  for (int f = 0; f < 64; ++f) { float d = h[f] - m; v += d * d; }
  v *= (1.f / 64.f);
  float rs = rsqrtf(v + 1e-5f);
  for (int f = 0; f < 64; ++f) {
    float val = (h[f] - m) * rs * g[f] + be[f];
    h[f] = val > 0.f ? val : 0.f;
  }
}

// ---------------------------------------------------------------------------
// Prep: blocks 0..1023 convert+tile weights to bf16 fragment order,
//       block 1024 computes the DPB MLP -> 64x64 bias table.
// wq_t layout: block (etile*8+kt) of 512 shorts; within: [lane][8] where
//   e = etile*16 + (lane&15), d = kt*32 + (lane>>4)*8 + el  -> a B-fragment
//   global load is  base + block*512 + lane*8  (perfectly coalesced 1KB).
// ---------------------------------------------------------------------------
__global__ __launch_bounds__(320)
void prep_kernel(const float* __restrict__ wqkv, const float* __restrict__ wout,
                 const float* __restrict__ w1, const float* __restrict__ b1,
                 const float* __restrict__ g1, const float* __restrict__ be1,
                 const float* __restrict__ w2, const float* __restrict__ b2,
                 const float* __restrict__ g2, const float* __restrict__ be2,
                 const float* __restrict__ w3, const float* __restrict__ b3,
                 const float* __restrict__ g3, const float* __restrict__ be3,
                 const float* __restrict__ w4, const float* __restrict__ b4,
                 short* __restrict__ wq_t, short* __restrict__ wo_t,
                 float* __restrict__ tblg) {
  __shared__ float h1buf[289 * 65];
  __shared__ float h2buf[289 * 65];
  __shared__ float sb[289];

  if (blockIdx.x < 1024) {
    int t = blockIdx.x * 320 + threadIdx.x;
    if (t < 196608) {
      int blk = t >> 9, within = t & 511;
      int l = within >> 3, el = within & 7;
      int et = blk >> 3, kt = blk & 7;
      int e = et * 16 + (l & 15);
      int d = kt * 32 + (l >> 4) * 8 + el;
      wq_t[t] = f2b(wqkv[e * 256 + d]);
    } else if (t < 262144) {
      int o = t - 196608;
      int blk = o >> 9, within = o & 511;
      int l = within >> 3, el = within & 7;
      int dt = blk >> 3, kt = blk & 7;
      int dout = dt * 16 + (l & 15);
      int e = kt * 32 + (l >> 4) * 8 + el;
      wo_t[o] = f2b(wout[dout * 256 + e]);
    }
    return;
  }

  // ---- DPB MLP block ----
  int t = threadIdx.x;
  bool act = (t < 289);
  int toff = t * 65;
  float y = (float)(t / 17) - 8.0f;
  float xx = (float)(t % 17) - 8.0f;
  if (act) {
    for (int f = 0; f < 64; ++f)
      h1buf[toff + f] = y * w1[2 * f] + xx * w1[2 * f + 1] + b1[f];
    lnrelu_lds(h1buf + toff, g1, be1);
    for (int f = 0; f < 64; ++f) {
      float a = b2[f];
      #pragma unroll 4
      for (int g = 0; g < 64; ++g) a += w2[f * 64 + g] * h1buf[toff + g];
      h2buf[toff + f] = a;
    }
    lnrelu_lds(h2buf + toff, g2, be2);
    for (int f = 0; f < 64; ++f) {
      float a = b3[f];
      #pragma unroll 4
      for (int g = 0; g < 64; ++g) a += w3[f * 64 + g] * h2buf[toff + g];
      h1buf[toff + f] = a;
    }
    lnrelu_lds(h1buf + toff, g3, be3);
    float o = b4[0];
    #pragma unroll 4
    for (int g = 0; g < 64; ++g) o += w4[g] * h1buf[toff + g];
    sb[t] = o;
  }
  __syncthreads();
  // expand to direct (i,j) table: idx quirk = (dy)*15 + (dx) into flat 17x17 MLP output
  for (int idx = t; idx < 4096; idx += 320) {
    int i = idx >> 6, j = idx & 63;
    int dy = (i >> 3) - (j >> 3) + 7;
    int dx = (i & 7) - (j & 7) + 7;
    tblg[idx] = sb[dy * 15 + dx];
  }
}

// ---------------------------------------------------------------------------
// Main fused kernel. LDS map (bytes), total 154112 (<160KiB, 1 block/CU):
//   [0      ,36864) xn [64][264] bf16   -> reused as 4x P-buf [64][72] bf16
//   [36864  ,71680) q  [8][64][32] bf16 -> reused as LN scratch (pre) and
//                                          ao [64][272] bf16 (post-sim)
//   [71680 ,104448) k  [8][64][32] bf16 \ reused as final f32 [64][257]
//   [104448,137472) vT [8][32][64] bf16 /  (after attention)
//   [137472,154112) bias table f32 [64][65]
// ---------------------------------------------------------------------------
#define LDS_XN    0
#define LDS_PBUF  0
#define LDS_Q     36864
#define LDS_AO    36864
#define LDS_SUMS  36864
#define LDS_SUMSQ 38912
#define LDS_MEAN  40960
#define LDS_RSTD  41216
#define LDS_K     71680
#define LDS_VT    104448
#define LDS_FIN   71680
#define LDS_TBL   137472
#define LDS_SIZE  154112

#define QK_SCALE 0.17677669529663687f  // 32^-0.5

__global__ __launch_bounds__(512, 2)
void attn_kernel(const float* __restrict__ x, const float* __restrict__ gnorm,
                 const float* __restrict__ bnorm, const short* __restrict__ wq_t,
                 const short* __restrict__ wo_t, const float* __restrict__ bout,
                 const float* __restrict__ tblg, float* __restrict__ out) {
  __shared__ __align__(16) char smem[LDS_SIZE];
  const int t = threadIdx.x;
  const int lane = t & 63;
  const int w = t >> 6;         // wave id 0..7 == head id
  const int r = lane & 15;
  const int gq = lane >> 4;

  // XCD-aware swizzle: adjacent windows (sharing cachelines) -> same XCD
  int bid = blockIdx.x;
  int wid = ((bid & 7) << 8) | (bid >> 3);
  const int b  = wid >> 10;
  const int wh = (wid >> 5) & 31;
  const int ww = wid & 31;

  // ---- stage bias table into LDS (padded [64][65]) ----
  {
    float* dst = (float*)(smem + LDS_TBL);
    #pragma unroll
    for (int e = 0; e < 8; ++e) {
      int idx = e * 512 + t;
      dst[(idx >> 6) * 65 + (idx & 63)] = tblg[idx];
    }
  }

  // ---- channel-first LayerNorm ----
  const int n = lane;                    // window position 0..63
  const int row = wh * 8 + (n >> 3);
  const int col = ww * 8 + (n & 7);
  const int d0 = w * 32;
  const float* xb = x + (((size_t)b * 256 + d0) << 16) + (row << 8) + col;
  float xv[32];
  float s1 = 0.f, s2 = 0.f;
  #pragma unroll
  for (int i = 0; i < 32; ++i) {
    float v = xb[(size_t)i << 16];
    xv[i] = v; s1 += v; s2 += v * v;
  }
  ((float*)(smem + LDS_SUMS))[w * 64 + n] = s1;
  ((float*)(smem + LDS_SUMSQ))[w * 64 + n] = s2;
  __syncthreads();
  if (t < 64) {
    float a = 0.f, q2 = 0.f;
    #pragma unroll
    for (int dg = 0; dg < 8; ++dg) {
      a  += ((float*)(smem + LDS_SUMS))[dg * 64 + t];
      q2 += ((float*)(smem + LDS_SUMSQ))[dg * 64 + t];
    }
    float mean = a * (1.f / 256.f);
    float var = q2 * (1.f / 256.f) - mean * mean;   // biased, matches jnp.var
    ((float*)(smem + LDS_MEAN))[t] = mean;
    ((float*)(smem + LDS_RSTD))[t] = rsqrtf(var + 1e-5f);
  }
  __syncthreads();
  {
    float mean = ((float*)(smem + LDS_MEAN))[n];
    float rstd = ((float*)(smem + LDS_RSTD))[n];
    #pragma unroll
    for (int c = 0; c < 4; ++c) {
      bf16x8 pk;
      #pragma unroll
      for (int e = 0; e < 8; ++e) {
        int i = c * 8 + e;
        int d = d0 + i;
        float xn = (xv[i] - mean) * rstd * gnorm[d] + bnorm[d];
        pk[e] = f2b(xn);
      }
      *(bf16x8*)(smem + LDS_XN + n * 528 + (d0 + c * 8) * 2) = pk;
    }
  }
  __syncthreads();

  const f32x4 vzero = {0.f, 0.f, 0.f, 0.f};

  // ---- QKV: 3 passes (q,k,v); wave w computes its own head's 64x32 chunk ----
  #pragma unroll 1
  for (int p = 0; p < 3; ++p) {
    f32x4 acc[4][2];
    #pragma unroll
    for (int mt = 0; mt < 4; ++mt)
      #pragma unroll
      for (int nt = 0; nt < 2; ++nt) acc[mt][nt] = vzero;
    #pragma unroll
    for (int kt = 0; kt < 8; ++kt) {
      bf16x8 bfr[2];
      #pragma unroll
      for (int nt = 0; nt < 2; ++nt)
        bfr[nt] = *(const bf16x8*)(wq_t + ((((p * 16 + w * 2 + nt) * 8 + kt) << 9) + lane * 8));
      bf16x8 afr[4];
      #pragma unroll
      for (int mt = 0; mt < 4; ++mt)
        afr[mt] = *(const bf16x8*)(smem + LDS_XN + (mt * 16 + r) * 528 + (kt * 32 + gq * 8) * 2);
      #pragma unroll
      for (int mt = 0; mt < 4; ++mt)
        #pragma unroll
        for (int nt = 0; nt < 2; ++nt)
          acc[mt][nt] = __builtin_amdgcn_mfma_f32_16x16x32_bf16(afr[mt], bfr[nt], acc[mt][nt], 0, 0, 0);
    }
    if (p == 0) {            // q: [64][32], scaled
      #pragma unroll
      for (int mt = 0; mt < 4; ++mt)
        #pragma unroll
        for (int nt = 0; nt < 2; ++nt)
          #pragma unroll
          for (int jj = 0; jj < 4; ++jj) {
            int nn = mt * 16 + gq * 4 + jj;
            int dh = nt * 16 + r;
            *(short*)(smem + LDS_Q + w * 4096 + nn * 64 + dh * 2) = f2b(acc[mt][nt][jj] * QK_SCALE);
          }
    } else if (p == 1) {     // k: [64][32]
      #pragma unroll
      for (int mt = 0; mt < 4; ++mt)
        #pragma unroll
        for (int nt = 0; nt < 2; ++nt)
          #pragma unroll
          for (int jj = 0; jj < 4; ++jj) {
            int nn = mt * 16 + gq * 4 + jj;
            int dh = nt * 16 + r;
            *(short*)(smem + LDS_K + w * 4096 + nn * 64 + dh * 2) = f2b(acc[mt][nt][jj]);
          }
    } else {                 // v transposed: [32 dh][64 j], packed b64 writes
      #pragma unroll
      for (int mt = 0; mt < 4; ++mt)
        #pragma unroll
        for (int nt = 0; nt < 2; ++nt) {
          bf16x4 pk;
          #pragma unroll
          for (int jj = 0; jj < 4; ++jj) pk[jj] = f2b(acc[mt][nt][jj]);
          *(bf16x4*)(smem + LDS_VT + w * 4096 + (nt * 16 + r) * 128 + (mt * 16 + gq * 4) * 2) = pk;
        }
    }
  }
  __threadfence_block();  // wave-local q/k/vT writes -> visible for cross-lane reads

  // ---- sim = q @ k^T  (per wave, own head), K=32 single step ----
  f32x4 s[4][4];
  {
    bf16x8 aq[4], bk[4];
    #pragma unroll
    for (int mt = 0; mt < 4; ++mt)
      aq[mt] = *(const bf16x8*)(smem + LDS_Q + w * 4096 + (mt * 16 + r) * 64 + gq * 16);
    #pragma unroll
    for (int nt = 0; nt < 4; ++nt)
      bk[nt] = *(const bf16x8*)(smem + LDS_K + w * 4096 + (nt * 16 + r) * 64 + gq * 16);
    #pragma unroll
    for (int mt = 0; mt < 4; ++mt)
      #pragma unroll
      for (int nt = 0; nt < 4; ++nt)
        s[mt][nt] = __builtin_amdgcn_mfma_f32_16x16x32_bf16(aq[mt], bk[nt], vzero, 0, 0, 0);
  }

  // ---- bias add + softmax (registers; rows split across 16-lane groups) ----
  float mm[4][4], pinv[4][4];
  #pragma unroll
  for (int mt = 0; mt < 4; ++mt)
    #pragma unroll
    for (int jj = 0; jj < 4; ++jj) {
      int i = mt * 16 + gq * 4 + jj;
      const float* trow = (const float*)(smem + LDS_TBL) + i * 65 + r;
      #pragma unroll
      for (int nt = 0; nt < 4; ++nt) s[mt][nt][jj] += trow[nt * 16];
      float v0 = fmaxf(fmaxf(s[mt][0][jj], s[mt][1][jj]), fmaxf(s[mt][2][jj], s[mt][3][jj]));
      v0 = fmaxf(v0, __shfl_xor(v0, 1));
      v0 = fmaxf(v0, __shfl_xor(v0, 2));
      v0 = fmaxf(v0, __shfl_xor(v0, 4));
      v0 = fmaxf(v0, __shfl_xor(v0, 8));
      mm[mt][jj] = v0;
    }
  #pragma unroll
  for (int mt = 0; mt < 4; ++mt)
    #pragma unroll
    for (int jj = 0; jj < 4; ++jj) {
      float a = 0.f;
      #pragma unroll
      for (int nt = 0; nt < 4; ++nt) {
        float e = exp2f((s[mt][nt][jj] - mm[mt][jj]) * 1.44269504088896f);
        s[mt][nt][jj] = e; a += e;
      }
      a += __shfl_xor(a, 1);
      a += __shfl_xor(a, 2);
      a += __shfl_xor(a, 4);
      a += __shfl_xor(a, 8);
      pinv[mt][jj] = 1.0f / a;
    }
  __syncthreads();   // all q/k/xn reads done; P-buf (over xn) & ao (over q) now writable

  // ---- P -> LDS, PV, ao writeback; two phase-halves share 4 P buffers ----
  char* pb = smem + LDS_PBUF + (w & 3) * 9216;  // [64][72] bf16
  #pragma unroll 1
  for (int ph = 0; ph < 2; ++ph) {
    if ((w >> 2) == ph) {
      #pragma unroll
      for (int mt = 0; mt < 4; ++mt)
        #pragma unroll
        for (int nt = 0; nt < 4; ++nt)
          #pragma unroll
          for (int jj = 0; jj < 4; ++jj) {
            int i = mt * 16 + gq * 4 + jj;
            int j = nt * 16 + r;
            *(short*)(pb + i * 144 + j * 2) = f2b(s[mt][nt][jj] * pinv[mt][jj]);
          }
      __threadfence_block();
      f32x4 o[4][2];
      #pragma unroll
      for (int mt = 0; mt < 4; ++mt)
        #pragma unroll
        for (int nt = 0; nt < 2; ++nt) o[mt][nt] = vzero;
      #pragma unroll
      for (int kt = 0; kt < 2; ++kt) {
        bf16x8 ap[4], bv[2];
        #pragma unroll
        for (int mt = 0; mt < 4; ++mt)
          ap[mt] = *(const bf16x8*)(pb + (mt * 16 + r) * 144 + (kt * 32 + gq * 8) * 2);
        #pragma unroll
        for (int nt = 0; nt < 2; ++nt)
          bv[nt] = *(const bf16x8*)(smem + LDS_VT + w * 4096 + (nt * 16 + r) * 128 + (kt * 32 + gq * 8) * 2);
        #pragma unroll
        for (int mt = 0; mt < 4; ++mt)
          #pragma unroll
          for (int nt = 0; nt < 2; ++nt)
            o[mt][nt] = __builtin_amdgcn_mfma_f32_16x16x32_bf16(ap[mt], bv[nt], o[mt][nt], 0, 0, 0);
      }
      #pragma unroll
      for (int mt = 0; mt < 4; ++mt)
        #pragma unroll
        for (int nt = 0; nt < 2; ++nt)
          #pragma unroll
          for (int jj = 0; jj < 4; ++jj) {
            int i = mt * 16 + gq * 4 + jj;
            int e = w * 32 + nt * 16 + r;
            *(short*)(smem + LDS_AO + i * 544 + e * 2) = f2b(o[mt][nt][jj]);
          }
    }
    __syncthreads();
  }

  // ---- out-proj: C[pos][dout] = ao @ w_out^T, wave w owns dout 32w..32w+31 ----
  f32x4 c[4][2];
  #pragma unroll
  for (int mt = 0; mt < 4; ++mt)
    #pragma unroll
    for (int nt = 0; nt < 2; ++nt) c[mt][nt] = vzero;
  #pragma unroll
  for (int kt = 0; kt < 8; ++kt) {
    bf16x8 b3[2];
    #pragma unroll
    for (int nt = 0; nt < 2; ++nt)
      b3[nt] = *(const bf16x8*)(wo_t + ((((w * 2 + nt) * 8 + kt) << 9) + lane * 8));
    bf16x8 a3[4];
    #pragma unroll
    for (int mt = 0; mt < 4; ++mt)
      a3[mt] = *(const bf16x8*)(smem + LDS_AO + (mt * 16 + r) * 544 + (kt * 32 + gq * 8) * 2);
    #pragma unroll
    for (int mt = 0; mt < 4; ++mt)
      #pragma unroll
      for (int nt = 0; nt < 2; ++nt)
        c[mt][nt] = __builtin_amdgcn_mfma_f32_16x16x32_bf16(a3[mt], b3[nt], c[mt][nt], 0, 0, 0);
  }
  {
    float bo0 = bout[w * 32 + r];
    float bo1 = bout[w * 32 + 16 + r];
    #pragma unroll
    for (int mt = 0; mt < 4; ++mt)
      #pragma unroll
      for (int nt = 0; nt < 2; ++nt)
        #pragma unroll
        for (int jj = 0; jj < 4; ++jj) {
          int i = mt * 16 + gq * 4 + jj;
          int dout = w * 32 + nt * 16 + r;
          ((float*)(smem + LDS_FIN))[i * 257 + dout] = c[mt][nt][jj] + (nt ? bo1 : bo0);
        }
  }
  __syncthreads();

  // ---- coalesced global write-out ----
  {
    const float* fin = (const float*)(smem + LDS_FIN);
    float* ob = out + (((size_t)b * 256 + w * 32) << 16) + (row << 8) + col;
    #pragma unroll
    for (int i2 = 0; i2 < 32; ++i2)
      ob[(size_t)i2 << 16] = fin[n * 257 + w * 32 + i2];
  }
}

// ---------------------------------------------------------------------------
extern "C" void kernel_launch(void* const* d_in, const int* in_sizes, int n_in,
                              void* d_out, int out_size, void* d_ws, size_t ws_size,
                              hipStream_t stream) {
  const float* x     = (const float*)d_in[0];
  const float* gnorm = (const float*)d_in[1];
  const float* bnorm = (const float*)d_in[2];
  const float* wqkv  = (const float*)d_in[3];
  const float* wout  = (const float*)d_in[4];
  const float* bout  = (const float*)d_in[5];
  const float* w1  = (const float*)d_in[6];
  const float* b1  = (const float*)d_in[7];
  const float* g1  = (const float*)d_in[8];
  const float* be1 = (const float*)d_in[9];
  const float* w2  = (const float*)d_in[10];
  const float* b2  = (const float*)d_in[11];
  const float* g2  = (const float*)d_in[12];
  const float* be2 = (const float*)d_in[13];
  const float* w3  = (const float*)d_in[14];
  const float* b3  = (const float*)d_in[15];
  const float* g3  = (const float*)d_in[16];
  const float* be3 = (const float*)d_in[17];
  const float* w4  = (const float*)d_in[18];
  const float* b4  = (const float*)d_in[19];

  short* wq_t = (short*)d_ws;                          // 393216 B
  short* wo_t = wq_t + 196608;                         // 131072 B
  float* tblg = (float*)((char*)d_ws + 524288);        // 16384 B

  prep_kernel<<<dim3(1025), dim3(320), 0, stream>>>(
      wqkv, wout, w1, b1, g1, be1, w2, b2, g2, be2, w3, b3, g3, be3, w4, b4,
      wq_t, wo_t, tblg);

  attn_kernel<<<dim3(2048), dim3(512), 0, stream>>>(
      x, gnorm, bnorm, wq_t, wo_t, bout, tblg, (float*)d_out);
}

// Round 2
// 293.989 us; speedup vs baseline: 1.8677x; 1.8677x over previous
//
#include <hip/hip_runtime.h>

// ---------------------------------------------------------------------------
// Fused windowed attention (CrossFormer-style short-distance attention).
// B=2, D=256, H=W=256, window 8x8 -> 2048 windows, HEADS=8, DHEAD=32.
// One 512-thread block per window, 68KB LDS -> 2 blocks/CU.
// bf16 MFMA (16x16x32), fp32 accumulate.
// ---------------------------------------------------------------------------

typedef __attribute__((ext_vector_type(8))) short bf16x8;
typedef __attribute__((ext_vector_type(4))) short bf16x4;
typedef __attribute__((ext_vector_type(4))) float f32x4;

__device__ __forceinline__ short f2b(float f) {
  union { float f; unsigned u; } v; v.f = f;
  unsigned r = v.u + 0x7FFFu + ((v.u >> 16) & 1u);  // RNE
  return (short)(r >> 16);
}

// ---------------------------------------------------------------------------
// Prep A: convert+tile weights to bf16 MFMA-fragment order (vectorized x8).
// wq_t layout: block (etile*8+kt) of 512 shorts; within: [lane][8] where
//   e = etile*16 + (lane&15), d = kt*32 + (lane>>4)*8 + el.
// ---------------------------------------------------------------------------
__global__ __launch_bounds__(256)
void wconv_kernel(const float* __restrict__ wqkv, const float* __restrict__ wout,
                  short* __restrict__ wq_t, short* __restrict__ wo_t) {
  int t = (blockIdx.x * 256 + threadIdx.x) * 8;
  if (t < 196608) {
    int blk = t >> 9, l = (t & 511) >> 3;
    int et = blk >> 3, kt = blk & 7;
    int e = et * 16 + (l & 15);
    int d = kt * 32 + (l >> 4) * 8;
    const float* src = wqkv + e * 256 + d;
    bf16x8 pk;
    #pragma unroll
    for (int el = 0; el < 8; ++el) pk[el] = f2b(src[el]);
    *(bf16x8*)(wq_t + t) = pk;
  } else if (t < 262144) {
    int o = t - 196608;
    int blk = o >> 9, l = (o & 511) >> 3;
    int dt = blk >> 3, kt = blk & 7;
    int dout = dt * 16 + (l & 15);
    int e = kt * 32 + (l >> 4) * 8;
    const float* src = wout + dout * 256 + e;
    bf16x8 pk;
    #pragma unroll
    for (int el = 0; el < 8; ++el) pk[el] = f2b(src[el]);
    *(bf16x8*)(wo_t + o) = pk;
  }
}

// ---------------------------------------------------------------------------
// Prep B: DPB MLP. One block (one wave, 64 threads) per grid position (289).
// Thread f owns feature f; LN via wave shuffles; weights staged in LDS with
// lane-rotated reads (conflict-free).
// ---------------------------------------------------------------------------
__device__ __forceinline__ float wave_sum64(float v) {
  v += __shfl_xor(v, 1);  v += __shfl_xor(v, 2);  v += __shfl_xor(v, 4);
  v += __shfl_xor(v, 8);  v += __shfl_xor(v, 16); v += __shfl_xor(v, 32);
  return v;
}

__global__ __launch_bounds__(64)
void dpb_kernel(const float* __restrict__ w1, const float* __restrict__ b1,
                const float* __restrict__ g1, const float* __restrict__ be1,
                const float* __restrict__ w2, const float* __restrict__ b2,
                const float* __restrict__ g2, const float* __restrict__ be2,
                const float* __restrict__ w3, const float* __restrict__ b3,
                const float* __restrict__ g3, const float* __restrict__ be3,
                const float* __restrict__ w4, const float* __restrict__ b4,
                float* __restrict__ tblr) {
  __shared__ float h[64];
  __shared__ float wbuf[4096];
  const int f = threadIdx.x;
  const int pos = blockIdx.x;
  const float py = (float)(pos / 17) - 8.0f;
  const float px = (float)(pos % 17) - 8.0f;

  // layer 1
  float a = py * w1[2 * f] + px * w1[2 * f + 1] + b1[f];
  {
    float m = wave_sum64(a) * (1.f / 64.f);
    float d = a - m;
    float var = wave_sum64(d * d) * (1.f / 64.f);
    a = fmaxf(d * rsqrtf(var + 1e-5f) * g1[f] + be1[f], 0.f);
  }
  h[f] = a;
  __threadfence_block();

  // layer 2
  #pragma unroll 8
  for (int k = 0; k < 64; ++k) wbuf[k * 64 + f] = w2[k * 64 + f];
  __threadfence_block();
  float acc = b2[f];
  #pragma unroll 8
  for (int k = 0; k < 64; ++k) {
    int g = (k + f) & 63;
    acc += wbuf[f * 64 + g] * h[g];
  }
  {
    float m = wave_sum64(acc) * (1.f / 64.f);
    float d = acc - m;
    float var = wave_sum64(d * d) * (1.f / 64.f);
    acc = fmaxf(d * rsqrtf(var + 1e-5f) * g2[f] + be2[f], 0.f);
  }
  __threadfence_block();
  h[f] = acc;
  __threadfence_block();

  // layer 3
  #pragma unroll 8
  for (int k = 0; k < 64; ++k) wbuf[k * 64 + f] = w3[k * 64 + f];
  __threadfence_block();
  float acc3 = b3[f];
  #pragma unroll 8
  for (int k = 0; k < 64; ++k) {
    int g = (k + f) & 63;
    acc3 += wbuf[f * 64 + g] * h[g];
  }
  {
    float m = wave_sum64(acc3) * (1.f / 64.f);
    float d = acc3 - m;
    float var = wave_sum64(d * d) * (1.f / 64.f);
    acc3 = fmaxf(d * rsqrtf(var + 1e-5f) * g3[f] + be3[f], 0.f);
  }

  // layer 4 (dot with w4)
  float o = wave_sum64(w4[f] * acc3);
  if (f == 0) tblr[pos] = o + b4[0];
}

// ---------------------------------------------------------------------------
// Main fused kernel. LDS map (bytes), total 68032 -> 2 blocks/CU:
//   [0    ,33792) xn [64][264] bf16  -> P 8x[64][32] bf16 xor3 (after bar4)
//                                    -> ao [64][256] bf16 xor7 (after bar5)
//   [34048,66816) per-wave 4KB buf: q[64][32]xor3 -> k (same) -> vT[32][64]xor7
//                 (pre-QKV: LN scratch sums/sumsq/mean/rstd)
//   [66816,68032) sb[289] f32 (raw DPB MLP output; bias looked up directly)
// ---------------------------------------------------------------------------
#define SM_XN    0
#define SM_P     0
#define SM_AO    0
#define SM_WB    34048
#define SM_SUMS  34048
#define SM_SUMSQ 36096
#define SM_MEAN  38144
#define SM_RSTD  38400
#define SM_SB    66816
#define SM_SIZE  68032

#define QK_SCALE 0.17677669529663687f  // 32^-0.5

__global__ __launch_bounds__(512, 4)
void attn_kernel(const float* __restrict__ x, const float* __restrict__ gnorm,
                 const float* __restrict__ bnorm, const short* __restrict__ wq_t,
                 const short* __restrict__ wo_t, const float* __restrict__ bout,
                 const float* __restrict__ tblr, float* __restrict__ out) {
  __shared__ __align__(16) char smem[SM_SIZE];
  const int t = threadIdx.x;
  const int lane = t & 63;
  const int w = t >> 6;         // wave id 0..7 == head id
  const int r = lane & 15;
  const int gq = lane >> 4;

  // XCD-aware swizzle: adjacent windows (sharing cachelines) -> same XCD
  int bid = blockIdx.x;
  int wid = ((bid & 7) << 8) | (bid >> 3);
  const int b  = wid >> 10;
  const int wh = (wid >> 5) & 31;
  const int ww = wid & 31;

  // ---- stage raw DPB output (289 floats) ----
  if (t < 289) ((float*)(smem + SM_SB))[t] = tblr[t];

  // ---- channel-first LayerNorm ----
  const int n = lane;                    // window position 0..63
  const int row = wh * 8 + (n >> 3);
  const int col = ww * 8 + (n & 7);
  const int d0 = w * 32;
  const float* xb = x + (((size_t)b * 256 + d0) << 16) + (row << 8) + col;
  float xv[32];
  float s1 = 0.f, s2 = 0.f;
  #pragma unroll
  for (int i = 0; i < 32; ++i) {
    float v = xb[(size_t)i << 16];
    xv[i] = v; s1 += v; s2 += v * v;
  }
  ((float*)(smem + SM_SUMS))[w * 64 + n] = s1;
  ((float*)(smem + SM_SUMSQ))[w * 64 + n] = s2;
  __syncthreads();                                              // bar1
  if (t < 64) {
    float a = 0.f, q2 = 0.f;
    #pragma unroll
    for (int dg = 0; dg < 8; ++dg) {
      a  += ((float*)(smem + SM_SUMS))[dg * 64 + t];
      q2 += ((float*)(smem + SM_SUMSQ))[dg * 64 + t];
    }
    float mean = a * (1.f / 256.f);
    float var = q2 * (1.f / 256.f) - mean * mean;   // biased, matches jnp.var
    ((float*)(smem + SM_MEAN))[t] = mean;
    ((float*)(smem + SM_RSTD))[t] = rsqrtf(var + 1e-5f);
  }
  __syncthreads();                                              // bar2
  {
    float mean = ((float*)(smem + SM_MEAN))[n];
    float rstd = ((float*)(smem + SM_RSTD))[n];
    #pragma unroll
    for (int c = 0; c < 4; ++c) {
      bf16x8 pk;
      #pragma unroll
      for (int e = 0; e < 8; ++e) {
        int i = c * 8 + e;
        int d = d0 + i;
        float xn = (xv[i] - mean) * rstd * gnorm[d] + bnorm[d];
        pk[e] = f2b(xn);
      }
      *(bf16x8*)(smem + SM_XN + n * 528 + (d0 + c * 8) * 2) = pk;
    }
  }
  __syncthreads();                                              // bar3

  const f32x4 vzero = {0.f, 0.f, 0.f, 0.f};
  char* wb = smem + SM_WB + w * 4096;
  bf16x8 aq[4], bk[4];

  // ---- QKV: 3 passes; wave w computes its own head's 64x32 chunk ----
  #pragma unroll 1
  for (int p = 0; p < 3; ++p) {
    f32x4 acc[4][2];
    #pragma unroll
    for (int mt = 0; mt < 4; ++mt)
      #pragma unroll
      for (int nt = 0; nt < 2; ++nt) acc[mt][nt] = vzero;
    #pragma unroll
    for (int kt = 0; kt < 8; ++kt) {
      bf16x8 bfr[2];
      #pragma unroll
      for (int nt = 0; nt < 2; ++nt)
        bfr[nt] = *(const bf16x8*)(wq_t + ((((p * 16 + w * 2 + nt) * 8 + kt) << 9) + lane * 8));
      bf16x8 afr[4];
      #pragma unroll
      for (int mt = 0; mt < 4; ++mt)
        afr[mt] = *(const bf16x8*)(smem + SM_XN + (mt * 16 + r) * 528 + (kt * 32 + gq * 8) * 2);
      #pragma unroll
      for (int mt = 0; mt < 4; ++mt)
        #pragma unroll
        for (int nt = 0; nt < 2; ++nt)
          acc[mt][nt] = __builtin_amdgcn_mfma_f32_16x16x32_bf16(afr[mt], bfr[nt], acc[mt][nt], 0, 0, 0);
    }
    if (p < 2) {
      // q (scaled) / k -> per-wave buf [64 pos][32 dh] bf16, xor ((pos&3)<<4)
      float sc = (p == 0) ? QK_SCALE : 1.0f;
      #pragma unroll
      for (int mt = 0; mt < 4; ++mt)
        #pragma unroll
        for (int nt = 0; nt < 2; ++nt)
          #pragma unroll
          for (int jj = 0; jj < 4; ++jj) {
            int nn = mt * 16 + gq * 4 + jj;
            int dh = nt * 16 + r;
            *(short*)(wb + nn * 64 + ((dh * 2) ^ ((nn & 3) << 4))) = f2b(acc[mt][nt][jj] * sc);
          }
      __threadfence_block();
      // read MFMA frags back (wave-local), then buffer is reusable
      if (p == 0) {
        #pragma unroll
        for (int mt = 0; mt < 4; ++mt)
          aq[mt] = *(const bf16x8*)(wb + (mt * 16 + r) * 64 + ((gq * 16) ^ ((r & 3) << 4)));
      } else {
        #pragma unroll
        for (int mt = 0; mt < 4; ++mt)
          bk[mt] = *(const bf16x8*)(wb + (mt * 16 + r) * 64 + ((gq * 16) ^ ((r & 3) << 4)));
      }
      __threadfence_block();
    } else {
      // vT -> per-wave buf [32 dh][64 pos] bf16, xor ((dh&7)<<4), b64 packs
      #pragma unroll
      for (int mt = 0; mt < 4; ++mt)
        #pragma unroll
        for (int nt = 0; nt < 2; ++nt) {
          bf16x4 pk;
          #pragma unroll
          for (int jj = 0; jj < 4; ++jj) pk[jj] = f2b(acc[mt][nt][jj]);
          int dh = nt * 16 + r;
          *(bf16x4*)(wb + dh * 128 + (((mt * 16 + gq * 4) * 2) ^ ((dh & 7) << 4))) = pk;
        }
      __threadfence_block();
    }
  }

  // ---- sim = q @ k^T (own head), from registers ----
  f32x4 s[4][4];
  #pragma unroll
  for (int mt = 0; mt < 4; ++mt)
    #pragma unroll
    for (int nt = 0; nt < 4; ++nt)
      s[mt][nt] = __builtin_amdgcn_mfma_f32_16x16x32_bf16(aq[mt], bk[nt], vzero, 0, 0, 0);

  // ---- bias add (direct sb lookup) + softmax; fold 1/sum into s ----
  {
    const float* sb = (const float*)(smem + SM_SB);
    int jy[4], jx[4];
    #pragma unroll
    for (int nt = 0; nt < 4; ++nt) {
      int j = nt * 16 + r;
      jy[nt] = (j >> 3); jx[nt] = (j & 7);
    }
    #pragma unroll
    for (int mt = 0; mt < 4; ++mt)
      #pragma unroll
      for (int jj = 0; jj < 4; ++jj) {
        int i = mt * 16 + gq * 4 + jj;
        int iy = (i >> 3) + 7, ix = (i & 7) + 7;
        #pragma unroll
        for (int nt = 0; nt < 4; ++nt)
          s[mt][nt][jj] += sb[(iy - jy[nt]) * 15 + (ix - jx[nt])];
        float v0 = fmaxf(fmaxf(s[mt][0][jj], s[mt][1][jj]), fmaxf(s[mt][2][jj], s[mt][3][jj]));
        v0 = fmaxf(v0, __shfl_xor(v0, 1));
        v0 = fmaxf(v0, __shfl_xor(v0, 2));
        v0 = fmaxf(v0, __shfl_xor(v0, 4));
        v0 = fmaxf(v0, __shfl_xor(v0, 8));
        float a = 0.f;
        #pragma unroll
        for (int nt = 0; nt < 4; ++nt) {
          float e = exp2f((s[mt][nt][jj] - v0) * 1.44269504088896f);
          s[mt][nt][jj] = e; a += e;
        }
        a += __shfl_xor(a, 1);
        a += __shfl_xor(a, 2);
        a += __shfl_xor(a, 4);
        a += __shfl_xor(a, 8);
        float pinv = 1.0f / a;
        #pragma unroll
        for (int nt = 0; nt < 4; ++nt) s[mt][nt][jj] *= pinv;
      }
  }
  __syncthreads();                                              // bar4: xn dead

  // ---- PV in two K-halves through per-wave P buf [64][32] bf16 xor3 ----
  char* pb = smem + SM_P + w * 4096;
  f32x4 o[4][2];
  #pragma unroll
  for (int mt = 0; mt < 4; ++mt)
    #pragma unroll
    for (int nt = 0; nt < 2; ++nt) o[mt][nt] = vzero;
  #pragma unroll 1
  for (int sh = 0; sh < 2; ++sh) {
    #pragma unroll
    for (int mt = 0; mt < 4; ++mt)
      #pragma unroll
      for (int nth = 0; nth < 2; ++nth)
        #pragma unroll
        for (int jj = 0; jj < 4; ++jj) {
          int i = mt * 16 + gq * 4 + jj;
          int jl = nth * 16 + r;
          *(short*)(pb + i * 64 + ((jl * 2) ^ ((i & 3) << 4))) = f2b(s[mt][2 * sh + nth][jj]);
        }
    __threadfence_block();
    bf16x8 ap[4], bv[2];
    #pragma unroll
    for (int mt = 0; mt < 4; ++mt)
      ap[mt] = *(const bf16x8*)(pb + (mt * 16 + r) * 64 + ((gq * 16) ^ ((r & 3) << 4)));
    #pragma unroll
    for (int nth = 0; nth < 2; ++nth)
      bv[nth] = *(const bf16x8*)(wb + (nth * 16 + r) * 128 + (((sh * 32 + gq * 8) * 2) ^ ((r & 7) << 4)));
    #pragma unroll
    for (int mt = 0; mt < 4; ++mt)
      #pragma unroll
      for (int nth = 0; nth < 2; ++nth)
        o[mt][nth] = __builtin_amdgcn_mfma_f32_16x16x32_bf16(ap[mt], bv[nth], o[mt][nth], 0, 0, 0);
    __threadfence_block();
  }
  __syncthreads();                                              // bar5: all PV done

  // ---- ao [64 pos][256 e] bf16 xor7 (over P region) ----
  #pragma unroll
  for (int mt = 0; mt < 4; ++mt)
    #pragma unroll
    for (int nth = 0; nth < 2; ++nth)
      #pragma unroll
      for (int jj = 0; jj < 4; ++jj) {
        int i = mt * 16 + gq * 4 + jj;
        int e = w * 32 + nth * 16 + r;
        *(short*)(smem + SM_AO + i * 512 + ((e * 2) ^ ((i & 7) << 4))) = f2b(o[mt][nth][jj]);
      }
  __syncthreads();                                              // bar6: ao ready

  // ---- out-proj TRANSPOSED: C[dout][pos] = wo . ao^T; wave w owns 32 douts.
  //      C-layout puts consecutive lanes on consecutive positions -> direct
  //      coalesced-ish global stores, no staging.
  f32x4 c[2][4];
  #pragma unroll
  for (int mtD = 0; mtD < 2; ++mtD)
    #pragma unroll
    for (int ntB = 0; ntB < 4; ++ntB) c[mtD][ntB] = vzero;
  #pragma unroll
  for (int kt = 0; kt < 8; ++kt) {
    bf16x8 awo[2];
    #pragma unroll
    for (int mtD = 0; mtD < 2; ++mtD)
      awo[mtD] = *(const bf16x8*)(wo_t + ((((w * 2 + mtD) * 8 + kt) << 9) + lane * 8));
    bf16x8 bao[4];
    #pragma unroll
    for (int ntB = 0; ntB < 4; ++ntB)
      bao[ntB] = *(const bf16x8*)(smem + SM_AO + (ntB * 16 + r) * 512 + (((kt * 32 + gq * 8) * 2) ^ ((r & 7) << 4)));
    #pragma unroll
    for (int mtD = 0; mtD < 2; ++mtD)
      #pragma unroll
      for (int ntB = 0; ntB < 4; ++ntB)
        c[mtD][ntB] = __builtin_amdgcn_mfma_f32_16x16x32_bf16(awo[mtD], bao[ntB], c[mtD][ntB], 0, 0, 0);
  }
  {
    float* obase = out + ((size_t)b << 24) + (wh * 8) * 256 + ww * 8;
    #pragma unroll
    for (int mtD = 0; mtD < 2; ++mtD)
      #pragma unroll
      for (int jj = 0; jj < 4; ++jj) {
        int dout = w * 32 + mtD * 16 + gq * 4 + jj;
        float bo = bout[dout];
        float* od = obase + ((size_t)dout << 16);
        #pragma unroll
        for (int ntB = 0; ntB < 4; ++ntB) {
          int i = ntB * 16 + r;
          od[(i >> 3) * 256 + (i & 7)] = c[mtD][ntB][jj] + bo;
        }
      }
  }
}

// ---------------------------------------------------------------------------
extern "C" void kernel_launch(void* const* d_in, const int* in_sizes, int n_in,
                              void* d_out, int out_size, void* d_ws, size_t ws_size,
                              hipStream_t stream) {
  const float* x     = (const float*)d_in[0];
  const float* gnorm = (const float*)d_in[1];
  const float* bnorm = (const float*)d_in[2];
  const float* wqkv  = (const float*)d_in[3];
  const float* wout  = (const float*)d_in[4];
  const float* bout  = (const float*)d_in[5];
  const float* w1  = (const float*)d_in[6];
  const float* b1  = (const float*)d_in[7];
  const float* g1  = (const float*)d_in[8];
  const float* be1 = (const float*)d_in[9];
  const float* w2  = (const float*)d_in[10];
  const float* b2  = (const float*)d_in[11];
  const float* g2  = (const float*)d_in[12];
  const float* be2 = (const float*)d_in[13];
  const float* w3  = (const float*)d_in[14];
  const float* b3  = (const float*)d_in[15];
  const float* g3  = (const float*)d_in[16];
  const float* be3 = (const float*)d_in[17];
  const float* w4  = (const float*)d_in[18];
  const float* b4  = (const float*)d_in[19];

  short* wq_t = (short*)d_ws;                          // 393216 B
  short* wo_t = wq_t + 196608;                         // 131072 B
  float* tblr = (float*)((char*)d_ws + 524288);        // 1156 B (289 f32)

  wconv_kernel<<<dim3(128), dim3(256), 0, stream>>>(wqkv, wout, wq_t, wo_t);
  dpb_kernel<<<dim3(289), dim3(64), 0, stream>>>(
      w1, b1, g1, be1, w2, b2, g2, be2, w3, b3, g3, be3, w4, b4, tblr);

  attn_kernel<<<dim3(2048), dim3(512), 0, stream>>>(
      x, gnorm, bnorm, wq_t, wo_t, bout, tblr, (float*)d_out);
}

// Round 3
// 248.008 us; speedup vs baseline: 2.2139x; 1.1854x over previous
//
#include <hip/hip_runtime.h>

// ---------------------------------------------------------------------------
// Fused windowed attention (CrossFormer-style SDA).
// B=2, D=256, H=W=256, window 8x8 -> 2048 windows, HEADS=8, DHEAD=32.
// One 512-thread block = 4 horizontally-adjacent windows (8 rows x 32 cols)
// so every global read/write is a full 128B run. 148KB LDS, 1 block/CU.
// bf16 MFMA 16x16x32 (GEMMs) + 16x16x16 (PV from registers), fp32 accum.
// ---------------------------------------------------------------------------

typedef __attribute__((ext_vector_type(8))) short bf16x8;
typedef __attribute__((ext_vector_type(4))) short bf16x4;
typedef __attribute__((ext_vector_type(4))) float f32x4;

__device__ __forceinline__ short f2b(float f) {
  union { float f; unsigned u; } v; v.f = f;
  unsigned r = v.u + 0x7FFFu + ((v.u >> 16) & 1u);  // RNE
  return (short)(r >> 16);
}

__device__ __forceinline__ f32x4 mfma16(bf16x4 a, bf16x4 b, f32x4 c) {
#if __has_builtin(__builtin_amdgcn_mfma_f32_16x16x16bf16_1k)
  return __builtin_amdgcn_mfma_f32_16x16x16bf16_1k(a, b, c, 0, 0, 0);
#else
  f32x4 d;
  asm volatile("v_mfma_f32_16x16x16_bf16 %0, %1, %2, %3"
               : "=&v"(d) : "v"(a), "v"(b), "v"(c));
  return d;
#endif
}

#define QK_SCALE 0.17677669529663687f  // 32^-0.5

// ---------------------------------------------------------------------------
// Prep A: convert+tile weights to bf16 MFMA-fragment order (vectorized x8).
// Layout: block (etile*8+kt) of 512 shorts; within: [lane][8] where
//   e = etile*16 + (lane&15), d = kt*32 + (lane>>4)*8 + el.
// QK_SCALE is folded into the q rows (e < 256).
// ---------------------------------------------------------------------------
__global__ __launch_bounds__(256)
void wconv_kernel(const float* __restrict__ wqkv, const float* __restrict__ wout,
                  short* __restrict__ wq_t, short* __restrict__ wo_t) {
  int t = (blockIdx.x * 256 + threadIdx.x) * 8;
  if (t < 196608) {
    int blk = t >> 9, l = (t & 511) >> 3;
    int et = blk >> 3, kt = blk & 7;
    int e = et * 16 + (l & 15);
    int d = kt * 32 + (l >> 4) * 8;
    const float* src = wqkv + e * 256 + d;
    float sc = (e < 256) ? QK_SCALE : 1.0f;
    bf16x8 pk;
    #pragma unroll
    for (int el = 0; el < 8; ++el) pk[el] = f2b(src[el] * sc);
    *(bf16x8*)(wq_t + t) = pk;
  } else if (t < 262144) {
    int o = t - 196608;
    int blk = o >> 9, l = (o & 511) >> 3;
    int dt = blk >> 3, kt = blk & 7;
    int dout = dt * 16 + (l & 15);
    int e = kt * 32 + (l >> 4) * 8;
    const float* src = wout + dout * 256 + e;
    bf16x8 pk;
    #pragma unroll
    for (int el = 0; el < 8; ++el) pk[el] = f2b(src[el]);
    *(bf16x8*)(wo_t + o) = pk;
  }
}

// ---------------------------------------------------------------------------
// Prep B: DPB MLP. One wave per grid position (289 blocks).
// ---------------------------------------------------------------------------
__device__ __forceinline__ float wave_sum64(float v) {
  v += __shfl_xor(v, 1);  v += __shfl_xor(v, 2);  v += __shfl_xor(v, 4);
  v += __shfl_xor(v, 8);  v += __shfl_xor(v, 16); v += __shfl_xor(v, 32);
  return v;
}

__global__ __launch_bounds__(64)
void dpb_kernel(const float* __restrict__ w1, const float* __restrict__ b1,
                const float* __restrict__ g1, const float* __restrict__ be1,
                const float* __restrict__ w2, const float* __restrict__ b2,
                const float* __restrict__ g2, const float* __restrict__ be2,
                const float* __restrict__ w3, const float* __restrict__ b3,
                const float* __restrict__ g3, const float* __restrict__ be3,
                const float* __restrict__ w4, const float* __restrict__ b4,
                float* __restrict__ tblr) {
  __shared__ float h[64];
  __shared__ float wbuf[4096];
  const int f = threadIdx.x;
  const int pos = blockIdx.x;
  const float py = (float)(pos / 17) - 8.0f;
  const float px = (float)(pos % 17) - 8.0f;

  float a = py * w1[2 * f] + px * w1[2 * f + 1] + b1[f];
  {
    float m = wave_sum64(a) * (1.f / 64.f);
    float d = a - m;
    float var = wave_sum64(d * d) * (1.f / 64.f);
    a = fmaxf(d * rsqrtf(var + 1e-5f) * g1[f] + be1[f], 0.f);
  }
  h[f] = a;
  __threadfence_block();

  #pragma unroll 8
  for (int k = 0; k < 64; ++k) wbuf[k * 64 + f] = w2[k * 64 + f];
  __threadfence_block();
  float acc = b2[f];
  #pragma unroll 8
  for (int k = 0; k < 64; ++k) {
    int g = (k + f) & 63;
    acc += wbuf[f * 64 + g] * h[g];
  }
  {
    float m = wave_sum64(acc) * (1.f / 64.f);
    float d = acc - m;
    float var = wave_sum64(d * d) * (1.f / 64.f);
    acc = fmaxf(d * rsqrtf(var + 1e-5f) * g2[f] + be2[f], 0.f);
  }
  __threadfence_block();
  h[f] = acc;
  __threadfence_block();

  #pragma unroll 8
  for (int k = 0; k < 64; ++k) wbuf[k * 64 + f] = w3[k * 64 + f];
  __threadfence_block();
  float acc3 = b3[f];
  #pragma unroll 8
  for (int k = 0; k < 64; ++k) {
    int g = (k + f) & 63;
    acc3 += wbuf[f * 64 + g] * h[g];
  }
  {
    float m = wave_sum64(acc3) * (1.f / 64.f);
    float d = acc3 - m;
    float var = wave_sum64(d * d) * (1.f / 64.f);
    acc3 = fmaxf(d * rsqrtf(var + 1e-5f) * g3[f] + be3[f], 0.f);
  }
  float o = wave_sum64(w4[f] * acc3);
  if (f == 0) tblr[pos] = o + b4[0];
}

// ---------------------------------------------------------------------------
// Main fused kernel. LDS (bytes):
//   [0     ,131072) XA [256 pos][256 ch] bf16, 5-bit XOR swizzle.
//                   pos p = wrow*32 + win*8 + wcol. xn before each window's
//                   QKV; overwritten in place by ao after that window's PV.
//   [131072,147456) per-wave 2KB scratch (q -> k -> vT in 2KB halves);
//                   overlaid during LN: sums/sumsq/mean/rstd (+0..4608),
//                   gnorm/bnorm staging (+8192, 2KB).
//   [147456,148640) sb[289] f32 (raw DPB MLP output).
// ---------------------------------------------------------------------------
#define SM_XA   0
#define SM_WS   131072
#define SM_GNB  (SM_WS + 8192)
#define SM_SB   147456
#define SM_SIZE 148640

#define XASWZ(p) ((((p) & 7) << 4) ^ ((((p) >> 3) & 3) << 7))

__global__ __launch_bounds__(512, 1)
void attn_kernel(const float* __restrict__ x, const float* __restrict__ gnorm,
                 const float* __restrict__ bnorm, const short* __restrict__ wq_t,
                 const short* __restrict__ wo_t, const float* __restrict__ bout,
                 const float* __restrict__ tblr, float* __restrict__ out) {
  __shared__ __align__(16) char smem[SM_SIZE];
  const int t = threadIdx.x;
  const int lane = t & 63;
  const int w = t >> 6;          // wave id 0..7 == head id
  const int r = lane & 15;
  const int gq = lane >> 4;

  const int bid = blockIdx.x;
  const int b   = bid >> 8;
  const int wh  = (bid >> 3) & 31;
  const int ww4 = bid & 7;
  const int R = wh * 8, C = ww4 * 32;

  // ---- stage sb + gnorm/bnorm ----
  if (t < 289) ((float*)(smem + SM_SB))[t] = tblr[t];
  if (t < 256) {
    ((float*)(smem + SM_GNB))[t]       = gnorm[t];
    ((float*)(smem + SM_GNB))[256 + t] = bnorm[t];
  }

  // ---- channel-first LayerNorm, 4 passes of 64 positions (2 rows x 32 cols)
  const int n = lane;
  const int d0 = w * 32;
  float* sums  = (float*)(smem + SM_WS);
  float* sumsq = sums + 512;
  float* meanb = sums + 1024;
  float* rstdb = meanb + 64;
  const float* gg = (const float*)(smem + SM_GNB);

  #pragma unroll 1
  for (int h = 0; h < 4; ++h) {
    const float* xb = x + (((size_t)(b * 256 + d0)) << 16) + (R + 2 * h) * 256 + C;
    const int off = (n >> 5) * 256 + (n & 31);
    float xv[32];
    float s1 = 0.f, s2v = 0.f;
    #pragma unroll
    for (int i = 0; i < 32; ++i) {
      float v = xb[((size_t)i << 16) + off];
      xv[i] = v; s1 += v; s2v += v * v;
    }
    sums[w * 64 + n] = s1;
    sumsq[w * 64 + n] = s2v;
    __syncthreads();
    if (t < 64) {
      float a = 0.f, q2 = 0.f;
      #pragma unroll
      for (int dg = 0; dg < 8; ++dg) {
        a  += sums[dg * 64 + t];
        q2 += sumsq[dg * 64 + t];
      }
      float mean = a * (1.f / 256.f);
      float var = q2 * (1.f / 256.f) - mean * mean;  // biased, matches jnp.var
      meanb[t] = mean;
      rstdb[t] = rsqrtf(var + 1e-5f);
    }
    __syncthreads();
    {
      float mean = meanb[n], rstd = rstdb[n];
      int p = h * 64 + n;
      #pragma unroll
      for (int c = 0; c < 4; ++c) {
        bf16x8 pk;
        #pragma unroll
        for (int e = 0; e < 8; ++e) {
          int i = c * 8 + e;
          int d = d0 + i;
          float xn = (xv[i] - mean) * rstd * gg[d] + gg[256 + d];
          pk[e] = f2b(xn);
        }
        *(bf16x8*)(smem + SM_XA + (p << 9) + ((((d0 + c * 8) << 1)) ^ XASWZ(p))) = pk;
      }
    }
  }
  __syncthreads();   // xn ready; LN scratch dead -> per-wave scratch usable

  const f32x4 vzero = {0.f, 0.f, 0.f, 0.f};
  char* ws = smem + SM_WS + w * 2048;

  // QKV GEMM macro: pass PP (0=q,1=k,2=v) for window `win` -> ACC[4][2]
  #define QKV_PASS(PP, ACC)                                                     \
    {                                                                           \
      _Pragma("unroll")                                                         \
      for (int mt = 0; mt < 4; ++mt)                                            \
        _Pragma("unroll")                                                       \
        for (int nt = 0; nt < 2; ++nt) ACC[mt][nt] = vzero;                     \
      _Pragma("unroll")                                                         \
      for (int kt = 0; kt < 8; ++kt) {                                          \
        bf16x8 bfr0 = *(const bf16x8*)(wq_t + (((((PP) * 16 + w * 2 + 0) * 8 + kt) << 9) + lane * 8)); \
        bf16x8 bfr1 = *(const bf16x8*)(wq_t + (((((PP) * 16 + w * 2 + 1) * 8 + kt) << 9) + lane * 8)); \
        bf16x8 afr[4];                                                          \
        _Pragma("unroll")                                                       \
        for (int mt = 0; mt < 4; ++mt) {                                        \
          int pmt = (mt * 2 + (r >> 3)) * 32 + win * 8 + (r & 7);               \
          afr[mt] = *(const bf16x8*)(smem + SM_XA + (pmt << 9) + ((((kt * 32 + gq * 8) << 1)) ^ XASWZ(pmt))); \
        }                                                                       \
        _Pragma("unroll")                                                       \
        for (int mt = 0; mt < 4; ++mt) {                                        \
          ACC[mt][0] = __builtin_amdgcn_mfma_f32_16x16x32_bf16(afr[mt], bfr0, ACC[mt][0], 0, 0, 0); \
          ACC[mt][1] = __builtin_amdgcn_mfma_f32_16x16x32_bf16(afr[mt], bfr1, ACC[mt][1], 0, 0, 0); \
        }                                                                       \
      }                                                                         \
    }

  // write q/k C-tiles (pos-half hf) into scratch [32 pos][32 dh], then read
  // back sim2 fragments [pos][dh 8-chunk] as bf16x8.
  #define QK_ROUNDTRIP(ACC, FRAGS)                                              \
    {                                                                           \
      _Pragma("unroll")                                                         \
      for (int hf = 0; hf < 2; ++hf) {                                          \
        _Pragma("unroll")                                                       \
        for (int mt = 2 * hf; mt < 2 * hf + 2; ++mt)                            \
          _Pragma("unroll")                                                     \
          for (int nt = 0; nt < 2; ++nt)                                        \
            _Pragma("unroll")                                                   \
            for (int jj = 0; jj < 4; ++jj) {                                    \
              int pos = mt * 16 + gq * 4 + jj;                                  \
              int dh = nt * 16 + r;                                             \
              *(short*)(ws + ((pos & 31) << 6) + ((dh << 1) ^ ((pos & 3) << 4))) = f2b(ACC[mt][nt][jj]); \
            }                                                                   \
        __threadfence_block();                                                  \
        _Pragma("unroll")                                                       \
        for (int jt = 2 * hf; jt < 2 * hf + 2; ++jt)                            \
          FRAGS[jt] = *(const bf16x8*)(ws + (((jt & 1) * 16 + r) << 6) + ((gq ^ (r & 3)) << 4)); \
        __threadfence_block();                                                  \
      }                                                                         \
    }

  #pragma unroll 1
  for (int win = 0; win < 4; ++win) {
    bf16x8 qf[4], kf[4];
    // ---- q, k ----
    {
      f32x4 acc[4][2];
      QKV_PASS(0, acc);
      QK_ROUNDTRIP(acc, qf);
    }
    {
      f32x4 acc[4][2];
      QKV_PASS(1, acc);
      QK_ROUNDTRIP(acc, kf);
    }

    // ---- sim^T = K . Q^T : lane (r,gq) holds S[i=it*16+r][j=jt*16+gq*4+jj]
    f32x4 s2[4][4];
    #pragma unroll
    for (int jt = 0; jt < 4; ++jt)
      #pragma unroll
      for (int it = 0; it < 4; ++it)
        s2[jt][it] = __builtin_amdgcn_mfma_f32_16x16x32_bf16(kf[jt], qf[it], vzero, 0, 0, 0);

    // ---- bias + softmax over j (local 16 values x 4 gq-lanes) ----
    {
      const float* sb = (const float*)(smem + SM_SB);
      int bjj[4];
      #pragma unroll
      for (int jj = 0; jj < 4; ++jj) {
        int jl = gq * 4 + jj;
        bjj[jj] = (jl >> 3) * 15 + (jl & 7);
      }
      #pragma unroll
      for (int it = 0; it < 4; ++it) {
        int ai = (it * 2 + (r >> 3)) * 15 + (r & 7) + 112;
        float m0 = -1e30f;
        #pragma unroll
        for (int jt = 0; jt < 4; ++jt)
          #pragma unroll
          for (int jj = 0; jj < 4; ++jj) {
            s2[jt][it][jj] += sb[ai - (jt * 30 + bjj[jj])];
            m0 = fmaxf(m0, s2[jt][it][jj]);
          }
        m0 = fmaxf(m0, __shfl_xor(m0, 16));
        m0 = fmaxf(m0, __shfl_xor(m0, 32));
        float sum = 0.f;
        #pragma unroll
        for (int jt = 0; jt < 4; ++jt)
          #pragma unroll
          for (int jj = 0; jj < 4; ++jj) {
            float e = exp2f((s2[jt][it][jj] - m0) * 1.44269504088896f);
            s2[jt][it][jj] = e; sum += e;
          }
        sum += __shfl_xor(sum, 16);
        sum += __shfl_xor(sum, 32);
        float pinv = 1.0f / sum;
        #pragma unroll
        for (int jt = 0; jt < 4; ++jt)
          #pragma unroll
          for (int jj = 0; jj < 4; ++jj) s2[jt][it][jj] *= pinv;
      }
    }
    // pack P -> bf16 B-fragments of 16x16x16 (k-chunk gq*4+jj matches layout)
    bf16x4 ppk[4][4];
    #pragma unroll
    for (int kt = 0; kt < 4; ++kt)
      #pragma unroll
      for (int it = 0; it < 4; ++it)
        #pragma unroll
        for (int jj = 0; jj < 4; ++jj) ppk[kt][it][jj] = f2b(s2[kt][it][jj]);

    // ---- v ----
    f32x4 vacc[4][2];
    QKV_PASS(2, vacc);

    __syncthreads();   // all waves done reading this window's xn rows

    // ---- vT halves + PV (O^T[dh][i], K=16 from registers) ----
    f32x4 o2[2][4];
    #pragma unroll
    for (int mtD = 0; mtD < 2; ++mtD)
      #pragma unroll
      for (int it = 0; it < 4; ++it) o2[mtD][it] = vzero;
    #pragma unroll
    for (int hf = 0; hf < 2; ++hf) {
      #pragma unroll
      for (int mt = 2 * hf; mt < 2 * hf + 2; ++mt)
        #pragma unroll
        for (int nt = 0; nt < 2; ++nt)
          #pragma unroll
          for (int jj = 0; jj < 4; ++jj) {
            int pos = mt * 16 + gq * 4 + jj;
            int dh = nt * 16 + r;
            *(short*)(ws + (dh << 6) + ((((pos & 31) << 1)) ^ ((dh & 7) << 3))) = f2b(vacc[mt][nt][jj]);
          }
      __threadfence_block();
      #pragma unroll
      for (int kt = 2 * hf; kt < 2 * hf + 2; ++kt) {
        bf16x4 va[2];
        #pragma unroll
        for (int mtD = 0; mtD < 2; ++mtD)
          va[mtD] = *(const bf16x4*)(ws + ((mtD * 16 + r) << 6) +
                                     (((((kt & 1) * 16 + gq * 4) << 1)) ^ ((r & 7) << 3)));
        #pragma unroll
        for (int mtD = 0; mtD < 2; ++mtD)
          #pragma unroll
          for (int it = 0; it < 4; ++it)
            o2[mtD][it] = mfma16(va[mtD], ppk[kt][it], o2[mtD][it]);
      }
      __threadfence_block();
    }

    // ---- ao into XA (overwrites this window's xn rows) ----
    #pragma unroll
    for (int mtD = 0; mtD < 2; ++mtD)
      #pragma unroll
      for (int it = 0; it < 4; ++it) {
        bf16x4 pk;
        #pragma unroll
        for (int jj = 0; jj < 4; ++jj) pk[jj] = f2b(o2[mtD][it][jj]);
        int p = (it * 2 + (r >> 3)) * 32 + win * 8 + (r & 7);
        int e = w * 32 + mtD * 16 + gq * 4;
        *(bf16x4*)(smem + SM_XA + (p << 9) + (((e << 1)) ^ XASWZ(p))) = pk;
      }
  }
  __syncthreads();   // all ao ready

  // ---- out-proj: C[dout][p] = wo . ao^T; wave w owns dout [32w,32w+32).
  bf16x8 woA[2][8];
  #pragma unroll
  for (int mtD = 0; mtD < 2; ++mtD)
    #pragma unroll
    for (int kt = 0; kt < 8; ++kt)
      woA[mtD][kt] = *(const bf16x8*)(wo_t + ((((w * 2 + mtD) * 8 + kt) << 9) + lane * 8));
  float bov[2][4];
  #pragma unroll
  for (int mtD = 0; mtD < 2; ++mtD)
    #pragma unroll
    for (int jj = 0; jj < 4; ++jj) bov[mtD][jj] = bout[w * 32 + mtD * 16 + gq * 4 + jj];

  #pragma unroll 1
  for (int ck = 0; ck < 4; ++ck) {
    f32x4 c3[2][4];
    #pragma unroll
    for (int mtD = 0; mtD < 2; ++mtD)
      #pragma unroll
      for (int itl = 0; itl < 4; ++itl) c3[mtD][itl] = vzero;
    #pragma unroll
    for (int kt = 0; kt < 8; ++kt) {
      bf16x8 bao[4];
      #pragma unroll
      for (int itl = 0; itl < 4; ++itl) {
        int p = ck * 64 + itl * 16 + r;
        bao[itl] = *(const bf16x8*)(smem + SM_XA + (p << 9) + ((((kt * 32 + gq * 8) << 1)) ^ XASWZ(p)));
      }
      #pragma unroll
      for (int mtD = 0; mtD < 2; ++mtD)
        #pragma unroll
        for (int itl = 0; itl < 4; ++itl)
          c3[mtD][itl] = __builtin_amdgcn_mfma_f32_16x16x32_bf16(woA[mtD][kt], bao[itl], c3[mtD][itl], 0, 0, 0);
    }
    #pragma unroll
    for (int mtD = 0; mtD < 2; ++mtD)
      #pragma unroll
      for (int jj = 0; jj < 4; ++jj) {
        int dout = w * 32 + mtD * 16 + gq * 4 + jj;
        float* od = out + (((size_t)(b * 256 + dout)) << 16) + R * 256 + C;
        #pragma unroll
        for (int itl = 0; itl < 4; ++itl) {
          int p = ck * 64 + itl * 16 + r;
          od[(p >> 5) * 256 + (p & 31)] = c3[mtD][itl][jj] + bov[mtD][jj];
        }
      }
  }
  #undef QKV_PASS
  #undef QK_ROUNDTRIP
}

// ---------------------------------------------------------------------------
extern "C" void kernel_launch(void* const* d_in, const int* in_sizes, int n_in,
                              void* d_out, int out_size, void* d_ws, size_t ws_size,
                              hipStream_t stream) {
  const float* x     = (const float*)d_in[0];
  const float* gnorm = (const float*)d_in[1];
  const float* bnorm = (const float*)d_in[2];
  const float* wqkv  = (const float*)d_in[3];
  const float* wout  = (const float*)d_in[4];
  const float* bout  = (const float*)d_in[5];
  const float* w1  = (const float*)d_in[6];
  const float* b1  = (const float*)d_in[7];
  const float* g1  = (const float*)d_in[8];
  const float* be1 = (const float*)d_in[9];
  const float* w2  = (const float*)d_in[10];
  const float* b2  = (const float*)d_in[11];
  const float* g2  = (const float*)d_in[12];
  const float* be2 = (const float*)d_in[13];
  const float* w3  = (const float*)d_in[14];
  const float* b3  = (const float*)d_in[15];
  const float* g3  = (const float*)d_in[16];
  const float* be3 = (const float*)d_in[17];
  const float* w4  = (const float*)d_in[18];
  const float* b4  = (const float*)d_in[19];

  short* wq_t = (short*)d_ws;                          // 393216 B
  short* wo_t = wq_t + 196608;                         // 131072 B
  float* tblr = (float*)((char*)d_ws + 524288);        // 1156 B

  wconv_kernel<<<dim3(128), dim3(256), 0, stream>>>(wqkv, wout, wq_t, wo_t);
  dpb_kernel<<<dim3(289), dim3(64), 0, stream>>>(
      w1, b1, g1, be1, w2, b2, g2, be2, w3, b3, g3, be3, w4, b4, tblr);

  attn_kernel<<<dim3(512), dim3(512), 0, stream>>>(
      x, gnorm, bnorm, wq_t, wo_t, bout, tblr, (float*)d_out);
}